// Round 1
// baseline (508.118 us; speedup 1.0000x reference)
//
#include <hip/hip_runtime.h>
#include <math.h>

#define B_    8
#define M_    2048
#define FIN_  256
#define FOUT_ 128
#define ALPHA_ 0.2f
#define NEG_INF_ -9.0e15f

#define TM_ 32
#define TN_ 64

// -------- kernel 1: h = x @ W  (64-row tile, fp32 vector GEMM) --------
__global__ __launch_bounds__(256) void k_xw(const float* __restrict__ x,
                                            const float* __restrict__ W,
                                            float* __restrict__ h) {
  const int tid = threadIdx.x;
  const int row0 = blockIdx.x * 64;
  const int f  = tid & 127;
  const int rg = tid >> 7;   // 0/1 -> rows rg*32 .. rg*32+31

  __shared__ float xs[64][68];     // 64 rows x 64-k chunk (+4 pad)
  __shared__ float ws[64][128];    // 64-k x 128-f chunk

  float acc[32];
#pragma unroll
  for (int i = 0; i < 32; ++i) acc[i] = 0.f;

  for (int kc = 0; kc < FIN_; kc += 64) {
#pragma unroll
    for (int i = 0; i < 4; ++i) {            // stage x tile: 4096 floats
      int idx = tid + i * 256;
      int r   = idx >> 4;
      int c4  = (idx & 15) << 2;
      float4 v = *(const float4*)(x + (size_t)(row0 + r) * FIN_ + kc + c4);
      *(float4*)&xs[r][c4] = v;
    }
#pragma unroll
    for (int i = 0; i < 8; ++i) {            // stage W tile: 8192 floats
      int idx = tid + i * 256;
      int kk  = idx >> 5;
      int c4  = (idx & 31) << 2;
      *(float4*)&ws[kk][c4] = *(const float4*)(W + (size_t)(kc + kk) * FOUT_ + c4);
    }
    __syncthreads();
#pragma unroll
    for (int kk = 0; kk < 64; kk += 4) {
      float w0 = ws[kk + 0][f];
      float w1 = ws[kk + 1][f];
      float w2 = ws[kk + 2][f];
      float w3 = ws[kk + 3][f];
#pragma unroll
      for (int r = 0; r < 32; ++r) {
        float4 xv = *(const float4*)&xs[rg * 32 + r][kk];
        acc[r] += xv.x * w0 + xv.y * w1 + xv.z * w2 + xv.w * w3;
      }
    }
    __syncthreads();
  }
#pragma unroll
  for (int r = 0; r < 32; ++r) {
    h[(size_t)(row0 + rg * 32 + r) * FOUT_ + f] = acc[r];
  }
}

// -------- kernel 2: f1[m] = h[m,:]·a1, f2[m] = h[m,:]·a2 --------
__global__ __launch_bounds__(128) void k_f12(const float* __restrict__ h,
                                             const float* __restrict__ a,
                                             float* __restrict__ f1,
                                             float* __restrict__ f2) {
  const int row = blockIdx.x;
  const int f = threadIdx.x;
  const float hv = h[(size_t)row * FOUT_ + f];
  float v1 = hv * a[f];
  float v2 = hv * a[FOUT_ + f];
#pragma unroll
  for (int off = 32; off >= 1; off >>= 1) {   // 64-lane wave reduce
    v1 += __shfl_xor(v1, off);
    v2 += __shfl_xor(v2, off);
  }
  __shared__ float s1[2], s2[2];
  const int w = f >> 6;
  if ((f & 63) == 0) { s1[w] = v1; s2[w] = v2; }
  __syncthreads();
  if (f == 0) {
    f1[row] = s1[0] + s1[1];
    f2[row] = s2[0] + s2[1];
  }
}

// -------- kernel 3: fused masked-softmax attention (flash-style) --------
// block = 256 thr, TM_=32 rows per block, TN_=64 col chunk.
// PV mapping: fg = tid&31 owns f = fg*4..+3 (float4), rgrp = tid>>5 owns 4 rows.
__global__ __launch_bounds__(256) void k_attn(const float* __restrict__ h,
                                              const int* __restrict__ adj,
                                              const float* __restrict__ f1,
                                              const float* __restrict__ f2,
                                              float* __restrict__ out) {
  const int tid = threadIdx.x;
  const int rows_blk = M_ / TM_;            // 64 blocks per batch
  const int b    = blockIdx.x / rows_blk;
  const int row0 = (blockIdx.x % rows_blk) * TM_;

  __shared__ float ss[TM_][TN_ + 4];        // scores -> P
  __shared__ float hs[TN_][FOUT_];          // h chunk (V)
  __shared__ float smx[TM_], ssum[TM_], sscale[TM_], f1s[TM_];

  if (tid < TM_) {
    smx[tid]  = -INFINITY;
    ssum[tid] = 0.f;
    f1s[tid]  = f1[b * M_ + row0 + tid];
  }

  const int fg   = tid & 31;
  const int rgrp = tid >> 5;
  const int ccol = tid & 63;     // scoring: col within chunk
  const int crow = tid >> 6;     // scoring: 4 rows per pass
  const int tr   = tid >> 3;     // softmax: row team (8 threads/row)
  const int ts   = tid & 7;

  float acc[4][4];
#pragma unroll
  for (int i = 0; i < 4; ++i)
#pragma unroll
    for (int j = 0; j < 4; ++j) acc[i][j] = 0.f;

  const size_t adj_row0 = (size_t)b * M_ * M_ + (size_t)row0 * M_;

  __syncthreads();

  for (int n0 = 0; n0 < M_; n0 += TN_) {
    // ---- stage h chunk (V) ----
#pragma unroll
    for (int i = 0; i < 8; ++i) {
      int idx = tid + i * 256;
      int c = idx >> 5;
      int q = (idx & 31) << 2;
      *(float4*)&hs[c][q] = *(const float4*)(h + (size_t)(b * M_ + n0 + c) * FOUT_ + q);
    }
    // ---- masked leaky-relu scores ----
    const float f2v = f2[b * M_ + n0 + ccol];
#pragma unroll
    for (int it = 0; it < 8; ++it) {
      int r = it * 4 + crow;
      int av = adj[adj_row0 + (size_t)r * M_ + n0 + ccol];
      float z = f1s[r] + f2v;
      float e = z > 0.f ? z : ALPHA_ * z;
      ss[r][ccol] = (av > 0) ? e : NEG_INF_;
    }
    __syncthreads();
    // ---- online softmax, 8-thread team per row ----
    float v[8];
    float cmax = -INFINITY;
#pragma unroll
    for (int j = 0; j < 8; ++j) {
      v[j] = ss[tr][ts * 8 + j];
      cmax = fmaxf(cmax, v[j]);
    }
#pragma unroll
    for (int off = 4; off >= 1; off >>= 1) cmax = fmaxf(cmax, __shfl_xor(cmax, off));
    const float m_old = smx[tr];
    const float m_new = fmaxf(m_old, cmax);
    const float scl = __expf(m_old - m_new);   // first chunk: exp(-inf)=0
    float psum = 0.f;
#pragma unroll
    for (int j = 0; j < 8; ++j) {
      float p = __expf(v[j] - m_new);
      ss[tr][ts * 8 + j] = p;
      psum += p;
    }
#pragma unroll
    for (int off = 4; off >= 1; off >>= 1) psum += __shfl_xor(psum, off);
    if (ts == 0) {
      smx[tr]    = m_new;
      ssum[tr]   = ssum[tr] * scl + psum;
      sscale[tr] = scl;
    }
    __syncthreads();
    // ---- PV accumulate (4 rows x 4 feats per thread) ----
#pragma unroll
    for (int rr = 0; rr < 4; ++rr) {
      const float sc = sscale[rgrp * 4 + rr];
      acc[rr][0] *= sc; acc[rr][1] *= sc; acc[rr][2] *= sc; acc[rr][3] *= sc;
    }
#pragma unroll
    for (int c4 = 0; c4 < TN_; c4 += 4) {
      float4 hv0 = *(const float4*)&hs[c4 + 0][fg * 4];
      float4 hv1 = *(const float4*)&hs[c4 + 1][fg * 4];
      float4 hv2 = *(const float4*)&hs[c4 + 2][fg * 4];
      float4 hv3 = *(const float4*)&hs[c4 + 3][fg * 4];
#pragma unroll
      for (int rr = 0; rr < 4; ++rr) {
        float4 pv = *(const float4*)&ss[rgrp * 4 + rr][c4];
        acc[rr][0] += pv.x * hv0.x + pv.y * hv1.x + pv.z * hv2.x + pv.w * hv3.x;
        acc[rr][1] += pv.x * hv0.y + pv.y * hv1.y + pv.z * hv2.y + pv.w * hv3.y;
        acc[rr][2] += pv.x * hv0.z + pv.y * hv1.z + pv.z * hv2.z + pv.w * hv3.z;
        acc[rr][3] += pv.x * hv0.w + pv.y * hv1.w + pv.z * hv2.w + pv.w * hv3.w;
      }
    }
    __syncthreads();
  }
  // ---- epilogue: divide by sum, ELU, store ----
#pragma unroll
  for (int rr = 0; rr < 4; ++rr) {
    const int r = rgrp * 4 + rr;
    const float inv = 1.0f / ssum[r];
    float4 o;
    float t;
    t = acc[rr][0] * inv; o.x = t > 0.f ? t : __expf(t) - 1.f;
    t = acc[rr][1] * inv; o.y = t > 0.f ? t : __expf(t) - 1.f;
    t = acc[rr][2] * inv; o.z = t > 0.f ? t : __expf(t) - 1.f;
    t = acc[rr][3] * inv; o.w = t > 0.f ? t : __expf(t) - 1.f;
    *(float4*)(out + (size_t)(b * M_ + row0 + r) * FOUT_ + fg * 4) = o;
  }
}

extern "C" void kernel_launch(void* const* d_in, const int* in_sizes, int n_in,
                              void* d_out, int out_size, void* d_ws, size_t ws_size,
                              hipStream_t stream) {
  const float* x   = (const float*)d_in[0];
  const int*   adj = (const int*)d_in[1];
  const float* W   = (const float*)d_in[2];
  const float* a   = (const float*)d_in[3];
  float* out = (float*)d_out;

  float* h  = (float*)d_ws;                          // 8*2048*128 fp32 = 8.4 MB
  float* f1 = h + (size_t)B_ * M_ * FOUT_;
  float* f2 = f1 + B_ * M_;

  hipLaunchKernelGGL(k_xw,   dim3((B_ * M_) / 64),     dim3(256), 0, stream, x, W, h);
  hipLaunchKernelGGL(k_f12,  dim3(B_ * M_),            dim3(128), 0, stream, h, a, f1, f2);
  hipLaunchKernelGGL(k_attn, dim3(B_ * (M_ / TM_)),    dim3(256), 0, stream, h, adj, f1, f2, out);
}

// Round 2
// 256.055 us; speedup vs baseline: 1.9844x; 1.9844x over previous
//
#include <hip/hip_runtime.h>
#include <math.h>

#define B_    8
#define M_    2048
#define FIN_  256
#define FOUT_ 128
#define ALPHA_ 0.2f
#define NEG_INF_ -9.0e15f

typedef unsigned short u16;
typedef __attribute__((ext_vector_type(8))) short bf16x8;
typedef __attribute__((ext_vector_type(4))) float f32x4;

static __device__ __forceinline__ u16 f2bf(float f) {
  union { float f; unsigned u; } v; v.f = f;
  unsigned r = v.u + 0x7FFFu + ((v.u >> 16) & 1u);   // RNE bf16
  return (u16)(r >> 16);
}

// -------- kernel 0: Wt[f][k] = bf16(W[k][f])  (128x256) --------
__global__ __launch_bounds__(256) void k_prep(const float* __restrict__ W,
                                              u16* __restrict__ Wt) {
  const int id = blockIdx.x * 256 + threadIdx.x;   // 32768 total
  const int f = id >> 8;
  const int k = id & 255;
  Wt[f * FIN_ + k] = f2bf(W[(size_t)k * FOUT_ + f]);
}

// -------- kernel 1: h = x@W via MFMA; fused f1/f2; store h^T bf16 --------
// grid 256 blocks x 256 thr; block = 64 rows; wave w owns rows w*16..+15, all 128 feats.
__global__ __launch_bounds__(256) void k_xw(const float* __restrict__ x,
                                            const u16* __restrict__ Wt,
                                            const float* __restrict__ a,
                                            u16* __restrict__ ht,
                                            float* __restrict__ f1,
                                            float* __restrict__ f2) {
  int blk = blockIdx.x;
  blk = (blk & 7) * 32 + (blk >> 3);          // XCD swizzle (256%8==0, bijective)
  const int b    = blk >> 5;
  const int row0 = blk * 64;                  // global flat row
  const int tid  = threadIdx.x;
  const int w  = tid >> 6;
  const int l  = tid & 63;
  const int lr = l & 15;
  const int g  = l >> 4;

  f32x4 acc[8];
#pragma unroll
  for (int ft = 0; ft < 8; ++ft) acc[ft] = (f32x4){0.f, 0.f, 0.f, 0.f};

  const float* xrow = x + (size_t)(row0 + w * 16 + lr) * FIN_;
#pragma unroll
  for (int ks = 0; ks < 8; ++ks) {
    float4 xa = *(const float4*)(xrow + ks * 32 + g * 8);
    float4 xc = *(const float4*)(xrow + ks * 32 + g * 8 + 4);
    bf16x8 af;
    af[0] = (short)f2bf(xa.x); af[1] = (short)f2bf(xa.y);
    af[2] = (short)f2bf(xa.z); af[3] = (short)f2bf(xa.w);
    af[4] = (short)f2bf(xc.x); af[5] = (short)f2bf(xc.y);
    af[6] = (short)f2bf(xc.z); af[7] = (short)f2bf(xc.w);
#pragma unroll
    for (int ft = 0; ft < 8; ++ft) {
      bf16x8 bf = *(const bf16x8*)(Wt + (ft * 16 + lr) * FIN_ + ks * 32 + g * 8);
      acc[ft] = __builtin_amdgcn_mfma_f32_16x16x32_bf16(af, bf, acc[ft], 0, 0, 0);
    }
  }

  // ---- fused f1/f2: f1[row] = sum_f h[row][f]*a1[f] ----
  float v1[4] = {0.f, 0.f, 0.f, 0.f};
  float v2[4] = {0.f, 0.f, 0.f, 0.f};
#pragma unroll
  for (int ft = 0; ft < 8; ++ft) {
    const float a1v = a[ft * 16 + lr];
    const float a2v = a[FOUT_ + ft * 16 + lr];
#pragma unroll
    for (int j = 0; j < 4; ++j) {
      v1[j] += acc[ft][j] * a1v;
      v2[j] += acc[ft][j] * a2v;
    }
  }
#pragma unroll
  for (int off = 1; off < 16; off <<= 1) {
#pragma unroll
    for (int j = 0; j < 4; ++j) {
      v1[j] += __shfl_xor(v1[j], off);
      v2[j] += __shfl_xor(v2[j], off);
    }
  }
  if (lr == 0) {
#pragma unroll
    for (int j = 0; j < 4; ++j) {
      const int rowg = row0 + w * 16 + g * 4 + j;
      f1[rowg] = v1[j];
      f2[rowg] = v2[j];
    }
  }

  // ---- h^T bf16 store via LDS transpose ----
  __shared__ float hs[64][130];
#pragma unroll
  for (int ft = 0; ft < 8; ++ft)
#pragma unroll
    for (int j = 0; j < 4; ++j)
      hs[w * 16 + g * 4 + j][ft * 16 + lr] = acc[ft][j];
  __syncthreads();

  const int f    = tid >> 1;
  const int half = tid & 1;
  union { u16 u[32]; uint4 q[4]; } hb;
#pragma unroll
  for (int i = 0; i < 32; ++i) hb.u[i] = f2bf(hs[half * 32 + i][f]);
  u16* dst = ht + ((size_t)(b * FOUT_ + f)) * M_ + (row0 & (M_ - 1)) + half * 32;
#pragma unroll
  for (int q = 0; q < 4; ++q) *(uint4*)(dst + q * 8) = hb.q[q];
}

// -------- kernel 2: fused masked-softmax attention, MFMA PV --------
// grid 1024 x 128 thr. Block = 16 rows; wave w owns feats w*64..+63. TN=128 chunks.
__global__ __launch_bounds__(128) void k_attn(const u16* __restrict__ ht,
                                              const int* __restrict__ adj,
                                              const float* __restrict__ f1,
                                              const float* __restrict__ f2,
                                              float* __restrict__ out) {
  int blk = blockIdx.x;
  blk = (blk & 7) * 128 + (blk >> 3);         // XCD swizzle (1024%8==0)
  const int b       = blk >> 7;
  const int row0loc = (blk & 127) * 16;
  const int tid = threadIdx.x;
  const int w  = tid >> 6;
  const int l  = tid & 63;
  const int lr = l & 15;
  const int g  = l >> 4;
  const int r  = tid >> 3;                    // score phase: 16 rows x 8 thr
  const int ts = tid & 7;

  __shared__ __align__(16) u16 P[16][128];    // bf16 P, XOR-swizzled by 16B slot
  __shared__ float smx[16], ssum[16], sscale[16], f1s[16];

  if (tid < 16) {
    smx[tid]  = -INFINITY;
    ssum[tid] = 0.f;
    f1s[tid]  = f1[b * M_ + row0loc + tid];
  }

  f32x4 acc[4];
#pragma unroll
  for (int ft = 0; ft < 4; ++ft) acc[ft] = (f32x4){0.f, 0.f, 0.f, 0.f};

  const int fbase = w * 64;
  const size_t adjrow = ((size_t)b * M_ + row0loc + r) * M_;
  const float* f2b = f2 + b * M_;
  char* Pb = (char*)P;

  __syncthreads();

  for (int n0 = 0; n0 < M_; n0 += 128) {
    // ---- scores: this thread owns cols [ts*8,+8) and [64+ts*8,+8) of the chunk ----
    const int c0 = n0 + ts * 8;
    const int c1 = n0 + 64 + ts * 8;
    int4 aj0 = *(const int4*)(adj + adjrow + c0);
    int4 aj1 = *(const int4*)(adj + adjrow + c0 + 4);
    int4 aj2 = *(const int4*)(adj + adjrow + c1);
    int4 aj3 = *(const int4*)(adj + adjrow + c1 + 4);
    float4 fa = *(const float4*)(f2b + c0);
    float4 fb = *(const float4*)(f2b + c0 + 4);
    float4 fc = *(const float4*)(f2b + c1);
    float4 fd = *(const float4*)(f2b + c1 + 4);
    const float f1r = f1s[r];
    int   aj[16] = {aj0.x, aj0.y, aj0.z, aj0.w, aj1.x, aj1.y, aj1.z, aj1.w,
                    aj2.x, aj2.y, aj2.z, aj2.w, aj3.x, aj3.y, aj3.z, aj3.w};
    float fv[16] = {fa.x, fa.y, fa.z, fa.w, fb.x, fb.y, fb.z, fb.w,
                    fc.x, fc.y, fc.z, fc.w, fd.x, fd.y, fd.z, fd.w};
    float s[16];
#pragma unroll
    for (int i = 0; i < 16; ++i) {
      float z = f1r + fv[i];
      float e = z > 0.f ? z : ALPHA_ * z;
      s[i] = aj[i] > 0 ? e : NEG_INF_;
    }
    // ---- online softmax (8-lane team per row) ----
    float cmax = s[0];
#pragma unroll
    for (int i = 1; i < 16; ++i) cmax = fmaxf(cmax, s[i]);
#pragma unroll
    for (int off = 1; off < 8; off <<= 1) cmax = fmaxf(cmax, __shfl_xor(cmax, off));
    const float m_old = smx[r];
    const float m_new = fmaxf(m_old, cmax);
    const float scl   = __expf(m_old - m_new);
    float psum = 0.f;
#pragma unroll
    for (int i = 0; i < 16; ++i) {
      float p = __expf(s[i] - m_new);
      s[i] = p;
      psum += p;
    }
#pragma unroll
    for (int off = 1; off < 8; off <<= 1) psum += __shfl_xor(psum, off);
    if (ts == 0) {
      smx[r]    = m_new;
      ssum[r]   = ssum[r] * scl + psum;
      sscale[r] = scl;
    }
    // ---- P -> bf16, swizzled LDS write (slots ts and ts+8) ----
    union { u16 u[8]; uint4 q; } w0, w1;
#pragma unroll
    for (int i = 0; i < 8; ++i) { w0.u[i] = f2bf(s[i]); w1.u[i] = f2bf(s[i + 8]); }
    *(uint4*)(Pb + r * 256 + ((ts ^ (r & 7)) << 4))       = w0.q;
    *(uint4*)(Pb + r * 256 + (((ts + 8) ^ (r & 7)) << 4)) = w1.q;
    __syncthreads();

    // ---- MFMA PV: rescale acc, then 16 MFMA per wave ----
    f32x4 scv = { sscale[g * 4], sscale[g * 4 + 1], sscale[g * 4 + 2], sscale[g * 4 + 3] };
#pragma unroll
    for (int ft = 0; ft < 4; ++ft) acc[ft] *= scv;
#pragma unroll
    for (int ks = 0; ks < 4; ++ks) {
      bf16x8 af = *(const bf16x8*)(Pb + lr * 256 + (((ks * 4 + g) ^ (lr & 7)) << 4));
#pragma unroll
      for (int ft = 0; ft < 4; ++ft) {
        const u16* hp = ht + ((size_t)(b * FOUT_ + fbase + ft * 16 + lr)) * M_
                        + n0 + ks * 32 + g * 8;
        bf16x8 bv = *(const bf16x8*)hp;
        acc[ft] = __builtin_amdgcn_mfma_f32_16x16x32_bf16(af, bv, acc[ft], 0, 0, 0);
      }
    }
    __syncthreads();
  }

  // ---- epilogue: 1/sum, ELU, store ----
  f32x4 inv = { 1.f / ssum[g * 4], 1.f / ssum[g * 4 + 1],
                1.f / ssum[g * 4 + 2], 1.f / ssum[g * 4 + 3] };
#pragma unroll
  for (int ft = 0; ft < 4; ++ft) {
#pragma unroll
    for (int j = 0; j < 4; ++j) {
      float t = acc[ft][j] * inv[j];
      float o = t > 0.f ? t : __expf(t) - 1.f;
      out[((size_t)b * M_ + row0loc + g * 4 + j) * FOUT_ + fbase + ft * 16 + lr] = o;
    }
  }
}

extern "C" void kernel_launch(void* const* d_in, const int* in_sizes, int n_in,
                              void* d_out, int out_size, void* d_ws, size_t ws_size,
                              hipStream_t stream) {
  const float* x   = (const float*)d_in[0];
  const int*   adj = (const int*)d_in[1];
  const float* W   = (const float*)d_in[2];
  const float* a   = (const float*)d_in[3];
  float* out = (float*)d_out;

  char* ws = (char*)d_ws;
  u16*   Wt = (u16*)ws;                        // 64 KB
  float* f1 = (float*)(ws + 65536);            // 64 KB
  float* f2 = (float*)(ws + 131072);           // 64 KB
  u16*   ht = (u16*)(ws + 196608);             // 4.2 MB  [B][128][2048] bf16

  hipLaunchKernelGGL(k_prep, dim3(128),  dim3(256), 0, stream, W, Wt);
  hipLaunchKernelGGL(k_xw,   dim3(256),  dim3(256), 0, stream, x, Wt, a, ht, f1, f2);
  hipLaunchKernelGGL(k_attn, dim3(1024), dim3(128), 0, stream, ht, adj, f1, f2, out);
}